// Round 9
// baseline (236.230 us; speedup 1.0000x reference)
//
#include <hip/hip_runtime.h>
#include <hip/hip_bf16.h>

typedef __bf16 bf16x8 __attribute__((ext_vector_type(8)));
typedef short  s16x4  __attribute__((ext_vector_type(4)));
typedef float  f32x16 __attribute__((ext_vector_type(16)));
typedef int    i32x2  __attribute__((ext_vector_type(2)));

constexpr int QN  = 128;   // query rows
constexpr int KN  = 2048;  // memory rows
constexpr int D5  = 768;
constexpr int SL  = 32;    // seq_len (t and s extent)
constexpr int ZD  = 24;    // per-token sub-dim
constexpr int KCH = 16;    // k's per block
constexpr int WPB = 8;     // waves per block

#if __has_builtin(__builtin_amdgcn_mfma_f32_32x32x8bf16_1k)
#define HAVE_MFMA_X8 1
#else
#define HAVE_MFMA_X8 0
#endif

#if __has_builtin(__builtin_amdgcn_permlane32_swap)
#define HAVE_PERMLANE32 1
#else
#define HAVE_PERMLANE32 0
#endif

static __device__ __forceinline__ float max3f(float a, float b, float c) {
    return fmaxf(fmaxf(a, b), c);   // fuses to v_max3_f32
}

static __device__ __forceinline__ float redmax16(const f32x16& a) {
    float x0 = max3f(a[0],  a[1],  a[2]);
    float x1 = max3f(a[3],  a[4],  a[5]);
    float x2 = max3f(a[6],  a[7],  a[8]);
    float x3 = max3f(a[9],  a[10], a[11]);
    float x4 = max3f(a[12], a[13], a[14]);
    float y0 = max3f(x0, x1, x2);
    float y1 = max3f(x3, x4, a[15]);
    return fmaxf(y0, y1);
}

// max with lane^32's value on the VALU (v_permlane32_swap), not LDS bpermute
static __device__ __forceinline__ float halfmax(float m) {
#if HAVE_PERMLANE32
    i32x2 pr = __builtin_amdgcn_permlane32_swap(__builtin_bit_cast(int, m),
                                                __builtin_bit_cast(int, m),
                                                false, false);
    return fmaxf(__builtin_bit_cast(float, pr[0]), __builtin_bit_cast(float, pr[1]));
#else
    return fmaxf(m, __shfl_xor(m, 32));
#endif
}

#if HAVE_MFMA_X8
static __device__ __forceinline__ short f2bfbits(float x) {
    __bf16 b = (__bf16)x;
    return __builtin_bit_cast(short, b);
}
#endif

struct accpair { f32x16 S, T; };

// R9: de-serialization round on the R4 base (best: ~34.6us, FETCH 4.7MB).
// R8 proved occupancy is NOT the lever (59% occ, still 47us); R7 proved LDS
// volume is not. Remaining stall mechanisms: (1) intra-wave serialization --
// at 44-VGPR the allocator keeps <=2 acc sets live, so pair i+1's MFMAs are
// NOT hoisted above pair i's acc-read/max tree; (2) inter-wave convoys --
// 8 waves leave the barrier in lockstep running identical code, bursting the
// same pipe together (MfmaUtil ~30% signature). Fixes: explicit 2-deep
// A/B-named software pipeline (MFMA(i+1) issued between MFMA(i) and
// reduce(i), all indices static per rule #20), and per-wave rotation of the
// pair order ((i + 2*wv) & 15) to de-phase the convoys at zero cost.
__global__ __launch_bounds__(512, 8) void matcher_kernel(const float* __restrict__ tgt,
                                                         const float* __restrict__ mem,
                                                         float* __restrict__ out)
{
    // K fragments: per k, chunk0 = 64 lanes x 16B (d0-15), chunk1 = 32 rows x 16B
    // (d16-23). 1536B per k. 24 KB total.
    __shared__ __align__(16) __bf16 Kf[KCH * 768];
    // Per-wave epilogue buffer: [pair][32 swizzled maxes]. 2 KB/wave, 16 KB.
    __shared__ float vbuf[WPB][KCH * 32];

    const int tid = threadIdx.x;
    const int qg  = blockIdx.x;   // 0..15  (8 q's per block)
    const int kc  = blockIdx.y;   // 0..127 (16 k's per block)
    const int k0  = kc * KCH;

    // ---- stage K chunk: fp32 -> bf16, MFMA fragment order (1 row/thread) ----
    {
        const int r  = tid;            // 512 threads == KCH*SL rows exactly
        const int kl = r >> 5;
        const int s  = r & 31;
        const float* src = mem + (size_t)(k0 + kl) * D5 + s * ZD;
        float tv[24];
#pragma unroll
        for (int j = 0; j < 6; ++j) ((float4*)tv)[j] = ((const float4*)src)[j];
        bf16x8 a, b, c;
#pragma unroll
        for (int j = 0; j < 8; ++j) {
            a[j] = (__bf16)tv[j];
            b[j] = (__bf16)tv[8 + j];
            c[j] = (__bf16)tv[16 + j];
        }
        __bf16* base = Kf + kl * 768;
        *(bf16x8*)(base +        s * 8)  = a;  // chunk0, lane s      (d 0-7)
        *(bf16x8*)(base + (32 +  s) * 8) = b;  // chunk0, lane s+32   (d 8-15)
        *(bf16x8*)(base + 512 +  s * 8)  = c;  // chunk1, row s       (d 16-23)
    }

    // ---- per-wave Q fragments (registers, live across the whole k-loop) ----
    const int lane = tid & 63;
    const int wv   = tid >> 6;   // 0..7
    const int t    = lane & 31;
    const int h    = lane >> 5;
    const int q    = qg * WPB + wv;

    const float4* p4 = (const float4*)(tgt + (size_t)q * D5 + t * ZD);
    bf16x8 aQ0;
    {
        float4 u0 = p4[2 * h], u1 = p4[2 * h + 1];  // d = h*8 .. h*8+7
        aQ0[0] = (__bf16)u0.x; aQ0[1] = (__bf16)u0.y; aQ0[2] = (__bf16)u0.z; aQ0[3] = (__bf16)u0.w;
        aQ0[4] = (__bf16)u1.x; aQ0[5] = (__bf16)u1.y; aQ0[6] = (__bf16)u1.z; aQ0[7] = (__bf16)u1.w;
    }
#if HAVE_MFMA_X8
    s16x4 aQ1;   // 32x32x8 fragment: lane holds d = 16 + h*4 + j
    {
        float4 w = p4[4 + h];
        aQ1[0] = f2bfbits(w.x); aQ1[1] = f2bfbits(w.y);
        aQ1[2] = f2bfbits(w.z); aQ1[3] = f2bfbits(w.w);
    }
#else
    bf16x8 aQ1;
    if (h == 0) {
        float4 w0 = p4[4], w1 = p4[5];              // d = 16..23
        aQ1[0] = (__bf16)w0.x; aQ1[1] = (__bf16)w0.y; aQ1[2] = (__bf16)w0.z; aQ1[3] = (__bf16)w0.w;
        aQ1[4] = (__bf16)w1.x; aQ1[5] = (__bf16)w1.y; aQ1[6] = (__bf16)w1.z; aQ1[7] = (__bf16)w1.w;
    } else {
#pragma unroll
        for (int j = 0; j < 8; ++j) aQ1[j] = (__bf16)0.0f;
    }
#endif

    f32x16 zacc;
#pragma unroll
    for (int i = 0; i < 16; ++i) zacc[i] = 0.0f;

    __syncthreads();

    float* vb = vbuf[wv];
    const int ro = wv << 1;      // per-wave rotation: de-phase the convoys

    // pair_mfma: both-orientation MFMAs for local pair kl (runtime-uniform kl
    // is fine: only LDS addressing depends on it; registers are named).
    auto pair_mfma = [&](int kl) -> accpair {
        const __bf16* lb = Kf + kl * 768;
        bf16x8 bK0 = *(const bf16x8*)(lb + lane * 8);
        accpair r;
#if HAVE_MFMA_X8
        s16x4 bK1 = *(const s16x4*)(lb + 512 + t * 8 + h * 4);
        r.S = __builtin_amdgcn_mfma_f32_32x32x16_bf16(aQ0, bK0, zacc, 0, 0, 0);
        r.S = __builtin_amdgcn_mfma_f32_32x32x8bf16_1k(aQ1, bK1, r.S, 0, 0, 0);
        r.T = __builtin_amdgcn_mfma_f32_32x32x16_bf16(bK0, aQ0, zacc, 0, 0, 0);
        r.T = __builtin_amdgcn_mfma_f32_32x32x8bf16_1k(bK1, aQ1, r.T, 0, 0, 0);
#else
        bf16x8 bK1 = *(const bf16x8*)(lb + 512 + t * 8);
        r.S = __builtin_amdgcn_mfma_f32_32x32x16_bf16(aQ0, bK0, zacc, 0, 0, 0);
        r.S = __builtin_amdgcn_mfma_f32_32x32x16_bf16(aQ1, bK1, r.S, 0, 0, 0);
        r.T = __builtin_amdgcn_mfma_f32_32x32x16_bf16(bK0, aQ0, zacc, 0, 0, 0);
        r.T = __builtin_amdgcn_mfma_f32_32x32x16_bf16(bK1, aQ1, r.T, 0, 0, 0);
#endif
        return r;
    };
    // reduce both orientations of one finished pair and store its 32 maxes.
    // accS: col=s, regs+halves span t -> max over t = score.max(axis=3)
    // accT: col=t, regs+halves span s -> max over s = score.max(axis=2)
    auto pair_reduce = [&](const accpair& a, int kl) {
        float m1 = halfmax(redmax16(a.S));
        float m2 = halfmax(redmax16(a.T));
        if (h == 0) vb[(kl << 5) + (t ^ kl)] = m1 + m2;   // conflict-free swizzle
    };

    // ---- 2-deep A/B software pipeline over the 16 pairs ----
    // Program order guarantees MFMA(i+1) sits between MFMA(i) and reduce(i):
    // the reduce's acc-read/max tree overlaps the next pair's matrix work.
    {
        accpair A = pair_mfma(ro & 15);
#pragma unroll
        for (int i = 0; i < 16; i += 2) {
            accpair B;
            if (i + 1 < 16) B = pair_mfma((i + 1 + ro) & 15);
            pair_reduce(A, (i + ro) & 15);
            if (i + 2 < 16) A = pair_mfma((i + 2 + ro) & 15);
            if (i + 1 < 16) pair_reduce(B, (i + 1 + ro) & 15);
        }
    }

    // ---- batched final phase (per wave, no barrier: same-wave LDS reuse) ----
    // Pair p's 32 values summed by lane pair (p, p+16); lanes 32-63 duplicate.
    {
        const int p    = lane & 15;
        const int half = (lane >> 4) & 1;
        float x[16];
#pragma unroll
        for (int i = 0; i < 16; ++i)
            x[i] = vb[(p << 5) + ((((half << 4) + i)) ^ p)];  // conflict-free reads
        float s0 = (x[0] + x[1]) + (x[2] + x[3]);
        float s1 = (x[4] + x[5]) + (x[6] + x[7]);
        float s2 = (x[8] + x[9]) + (x[10] + x[11]);
        float s3 = (x[12] + x[13]) + (x[14] + x[15]);
        float sum = (s0 + s1) + (s2 + s3);
        sum += __shfl_xor(sum, 16);           // combine halves of the 32-sum
        float r = 1.0f / (1.0f + __expf(-sum * (1.0f / 64.0f)));
        if (lane < 16) {
            const int idx = q * KN + k0 + p;
            out[idx] = r;                     // output 0
            out[idx + QN * KN] = r;           // output 1 (tuple repeats score_p)
        }
    }
}

extern "C" void kernel_launch(void* const* d_in, const int* in_sizes, int n_in,
                              void* d_out, int out_size, void* d_ws, size_t ws_size,
                              hipStream_t stream)
{
    const float* tgt = (const float*)d_in[0];
    const float* mem = (const float*)d_in[1];
    float* out = (float*)d_out;
    dim3 grid(QN / WPB, KN / KCH);   // (16, 128) — R4 locality structure
    matcher_kernel<<<grid, 512, 0, stream>>>(tgt, mem, out);
}

// Round 10
// 92.060 us; speedup vs baseline: 2.5660x; 2.5660x over previous
//
#include <hip/hip_runtime.h>
#include <hip/hip_bf16.h>

typedef __bf16 bf16x8 __attribute__((ext_vector_type(8)));
typedef short  s16x4  __attribute__((ext_vector_type(4)));
typedef float  f32x16 __attribute__((ext_vector_type(16)));
typedef int    i32x2  __attribute__((ext_vector_type(2)));

constexpr int QN  = 128;   // query rows
constexpr int KN  = 2048;  // memory rows
constexpr int D5  = 768;
constexpr int SL  = 32;    // seq_len (t and s extent)
constexpr int ZD  = 24;    // per-token sub-dim
constexpr int KCH = 16;    // k's per block
constexpr int WPB = 8;     // waves per block

#if __has_builtin(__builtin_amdgcn_mfma_f32_32x32x8bf16_1k)
#define HAVE_MFMA_X8 1
#else
#define HAVE_MFMA_X8 0
#endif

#if __has_builtin(__builtin_amdgcn_permlane32_swap)
#define HAVE_PERMLANE32 1
#else
#define HAVE_PERMLANE32 0
#endif

static __device__ __forceinline__ float max3f(float a, float b, float c) {
    return fmaxf(fmaxf(a, b), c);   // fuses to v_max3_f32
}

static __device__ __forceinline__ float redmax16(const f32x16& a) {
    float x0 = max3f(a[0],  a[1],  a[2]);
    float x1 = max3f(a[3],  a[4],  a[5]);
    float x2 = max3f(a[6],  a[7],  a[8]);
    float x3 = max3f(a[9],  a[10], a[11]);
    float x4 = max3f(a[12], a[13], a[14]);
    float y0 = max3f(x0, x1, x2);
    float y1 = max3f(x3, x4, a[15]);
    return fmaxf(y0, y1);
}

// max with lane^32's value on the VALU (v_permlane32_swap), not LDS bpermute
static __device__ __forceinline__ float halfmax(float m) {
#if HAVE_PERMLANE32
    i32x2 pr = __builtin_amdgcn_permlane32_swap(__builtin_bit_cast(int, m),
                                                __builtin_bit_cast(int, m),
                                                false, false);
    return fmaxf(__builtin_bit_cast(float, pr[0]), __builtin_bit_cast(float, pr[1]));
#else
    return fmaxf(m, __shfl_xor(m, 32));
#endif
}

#if HAVE_MFMA_X8
static __device__ __forceinline__ short f2bfbits(float x) {
    __bf16 b = (__bf16)x;
    return __builtin_bit_cast(short, b);
}
#endif

// R10: R9's 2-deep pipeline, register-budget corrected. R9's 181us was NOT a
// test of the pipeline: __launch_bounds__(512,8) caps the allocator at 64
// VGPRs/wave (waves/SIMD budget 512/8), while 2-deep needs 64 regs of
// accumulators alone -> total scratch spill (VGPR_Count=32, WRITE 428MB).
// Fixes: (a) __launch_bounds__(512,4) -> 128-reg budget (pipeline state
// ~115 regs fits); (b) no lambda/struct-by-value: inlined helper writes
// NAMED f32x16& out-params, all indices compile-time after full unroll
// (rule #20); (c) per-wave rotation kept (free convoy de-phasing).
// Theory unchanged: R4's 34.6us == serial sum of pipe demands (matrix 13.8
// + LDS ~9 + VALU ~8); program-ordering MFMA(i+1) between MFMA(i) and
// reduce(i) overlaps matrix and VALU pipes -> toward the ~14-20us max regime.

static __device__ __forceinline__ void pair_mfma(const __bf16* __restrict__ Kf, int kl,
                                                 int lane, int t, int h,
                                                 const bf16x8& aQ0,
#if HAVE_MFMA_X8
                                                 const s16x4& aQ1,
#else
                                                 const bf16x8& aQ1,
#endif
                                                 const f32x16& zacc,
                                                 f32x16& S, f32x16& T)
{
    const __bf16* lb = Kf + kl * 768;
    bf16x8 bK0 = *(const bf16x8*)(lb + lane * 8);
#if HAVE_MFMA_X8
    s16x4 bK1 = *(const s16x4*)(lb + 512 + t * 8 + h * 4);
    S = __builtin_amdgcn_mfma_f32_32x32x16_bf16(aQ0, bK0, zacc, 0, 0, 0);
    S = __builtin_amdgcn_mfma_f32_32x32x8bf16_1k(aQ1, bK1, S, 0, 0, 0);
    T = __builtin_amdgcn_mfma_f32_32x32x16_bf16(bK0, aQ0, zacc, 0, 0, 0);
    T = __builtin_amdgcn_mfma_f32_32x32x8bf16_1k(bK1, aQ1, T, 0, 0, 0);
#else
    bf16x8 bK1 = *(const bf16x8*)(lb + 512 + t * 8);
    S = __builtin_amdgcn_mfma_f32_32x32x16_bf16(aQ0, bK0, zacc, 0, 0, 0);
    S = __builtin_amdgcn_mfma_f32_32x32x16_bf16(aQ1, bK1, S, 0, 0, 0);
    T = __builtin_amdgcn_mfma_f32_32x32x16_bf16(bK0, aQ0, zacc, 0, 0, 0);
    T = __builtin_amdgcn_mfma_f32_32x32x16_bf16(bK1, aQ1, T, 0, 0, 0);
#endif
}

// accS: col=s, regs+halves span t -> max over t = score.max(axis=3)
// accT: col=t, regs+halves span s -> max over s = score.max(axis=2)
static __device__ __forceinline__ void pair_reduce(const f32x16& S, const f32x16& T,
                                                   int kl, int t, int h,
                                                   float* __restrict__ vb)
{
    float m1 = halfmax(redmax16(S));
    float m2 = halfmax(redmax16(T));
    if (h == 0) vb[(kl << 5) + (t ^ kl)] = m1 + m2;   // conflict-free swizzle
}

__global__ __launch_bounds__(512, 4) void matcher_kernel(const float* __restrict__ tgt,
                                                         const float* __restrict__ mem,
                                                         float* __restrict__ out)
{
    // K fragments: per k, chunk0 = 64 lanes x 16B (d0-15), chunk1 = 32 rows x 16B
    // (d16-23). 1536B per k. 24 KB total.
    __shared__ __align__(16) __bf16 Kf[KCH * 768];
    // Per-wave epilogue buffer: [pair][32 swizzled maxes]. 2 KB/wave, 16 KB.
    __shared__ float vbuf[WPB][KCH * 32];

    const int tid = threadIdx.x;
    const int qg  = blockIdx.x;   // 0..15  (8 q's per block)
    const int kc  = blockIdx.y;   // 0..127 (16 k's per block)
    const int k0  = kc * KCH;

    // ---- stage K chunk: fp32 -> bf16, MFMA fragment order (1 row/thread) ----
    {
        const int r  = tid;            // 512 threads == KCH*SL rows exactly
        const int kl = r >> 5;
        const int s  = r & 31;
        const float* src = mem + (size_t)(k0 + kl) * D5 + s * ZD;
        float tv[24];
#pragma unroll
        for (int j = 0; j < 6; ++j) ((float4*)tv)[j] = ((const float4*)src)[j];
        bf16x8 a, b, c;
#pragma unroll
        for (int j = 0; j < 8; ++j) {
            a[j] = (__bf16)tv[j];
            b[j] = (__bf16)tv[8 + j];
            c[j] = (__bf16)tv[16 + j];
        }
        __bf16* base = Kf + kl * 768;
        *(bf16x8*)(base +        s * 8)  = a;  // chunk0, lane s      (d 0-7)
        *(bf16x8*)(base + (32 +  s) * 8) = b;  // chunk0, lane s+32   (d 8-15)
        *(bf16x8*)(base + 512 +  s * 8)  = c;  // chunk1, row s       (d 16-23)
    }

    // ---- per-wave Q fragments (registers, live across the whole k-loop) ----
    const int lane = tid & 63;
    const int wv   = tid >> 6;   // 0..7
    const int t    = lane & 31;
    const int h    = lane >> 5;
    const int q    = qg * WPB + wv;

    const float4* p4 = (const float4*)(tgt + (size_t)q * D5 + t * ZD);
    bf16x8 aQ0;
    {
        float4 u0 = p4[2 * h], u1 = p4[2 * h + 1];  // d = h*8 .. h*8+7
        aQ0[0] = (__bf16)u0.x; aQ0[1] = (__bf16)u0.y; aQ0[2] = (__bf16)u0.z; aQ0[3] = (__bf16)u0.w;
        aQ0[4] = (__bf16)u1.x; aQ0[5] = (__bf16)u1.y; aQ0[6] = (__bf16)u1.z; aQ0[7] = (__bf16)u1.w;
    }
#if HAVE_MFMA_X8
    s16x4 aQ1;   // 32x32x8 fragment: lane holds d = 16 + h*4 + j
    {
        float4 w = p4[4 + h];
        aQ1[0] = f2bfbits(w.x); aQ1[1] = f2bfbits(w.y);
        aQ1[2] = f2bfbits(w.z); aQ1[3] = f2bfbits(w.w);
    }
#else
    bf16x8 aQ1;
    if (h == 0) {
        float4 w0 = p4[4], w1 = p4[5];              // d = 16..23
        aQ1[0] = (__bf16)w0.x; aQ1[1] = (__bf16)w0.y; aQ1[2] = (__bf16)w0.z; aQ1[3] = (__bf16)w0.w;
        aQ1[4] = (__bf16)w1.x; aQ1[5] = (__bf16)w1.y; aQ1[6] = (__bf16)w1.z; aQ1[7] = (__bf16)w1.w;
    } else {
#pragma unroll
        for (int j = 0; j < 8; ++j) aQ1[j] = (__bf16)0.0f;
    }
#endif

    f32x16 zacc;
#pragma unroll
    for (int i = 0; i < 16; ++i) zacc[i] = 0.0f;

    __syncthreads();

    float* vb = vbuf[wv];
    const int ro = wv << 1;      // per-wave rotation: de-phase the convoys

    // ---- 2-deep A/B software pipeline over the 16 pairs ----
    // Program order puts MFMA(i+1) between MFMA(i) and reduce(i): the
    // reduce's acc-read/max tree overlaps the next pair's matrix work.
    {
        f32x16 sA, tA, sB, tB;
        pair_mfma(Kf, ro & 15, lane, t, h, aQ0, aQ1, zacc, sA, tA);
#pragma unroll
        for (int i = 0; i < 16; i += 2) {
            if (i + 1 < 16) pair_mfma(Kf, (i + 1 + ro) & 15, lane, t, h, aQ0, aQ1, zacc, sB, tB);
            pair_reduce(sA, tA, (i + ro) & 15, t, h, vb);
            if (i + 2 < 16) pair_mfma(Kf, (i + 2 + ro) & 15, lane, t, h, aQ0, aQ1, zacc, sA, tA);
            if (i + 1 < 16) pair_reduce(sB, tB, (i + 1 + ro) & 15, t, h, vb);
        }
    }

    // ---- batched final phase (per wave, no barrier: same-wave LDS reuse) ----
    // Pair p's 32 values summed by lane pair (p, p+16); lanes 32-63 duplicate.
    {
        const int p    = lane & 15;
        const int half = (lane >> 4) & 1;
        float x[16];
#pragma unroll
        for (int i = 0; i < 16; ++i)
            x[i] = vb[(p << 5) + ((((half << 4) + i)) ^ p)];  // conflict-free reads
        float s0 = (x[0] + x[1]) + (x[2] + x[3]);
        float s1 = (x[4] + x[5]) + (x[6] + x[7]);
        float s2 = (x[8] + x[9]) + (x[10] + x[11]);
        float s3 = (x[12] + x[13]) + (x[14] + x[15]);
        float sum = (s0 + s1) + (s2 + s3);
        sum += __shfl_xor(sum, 16);           // combine halves of the 32-sum
        float r = 1.0f / (1.0f + __expf(-sum * (1.0f / 64.0f)));
        if (lane < 16) {
            const int idx = q * KN + k0 + p;
            out[idx] = r;                     // output 0
            out[idx + QN * KN] = r;           // output 1 (tuple repeats score_p)
        }
    }
}

extern "C" void kernel_launch(void* const* d_in, const int* in_sizes, int n_in,
                              void* d_out, int out_size, void* d_ws, size_t ws_size,
                              hipStream_t stream)
{
    const float* tgt = (const float*)d_in[0];
    const float* mem = (const float*)d_in[1];
    float* out = (float*)d_out;
    dim3 grid(QN / WPB, KN / KCH);   // (16, 128) — R4 locality structure
    matcher_kernel<<<grid, 512, 0, stream>>>(tgt, mem, out);
}